// Round 9
// baseline (435.712 us; speedup 1.0000x reference)
//
#include <hip/hip_runtime.h>
#include <hip/hip_cooperative_groups.h>

namespace cg = cooperative_groups;

// v18: v16 stage-C (dist-2 weight prefetch — v17's full-tap prefetch REVERTED,
// it raised FETCH 26->29MB and regressed) + GN FUSION via cooperative launch:
//  - k_deform tail: pstats -> threadfence -> grid.sync -> per-n pstats reduce
//    -> affine(+relu / +residual+relu) applied to IN-REGISTER acc -> store.
//  - raw round-trip eliminated both rounds (32 MB); k_gn_relu & k_gn_final
//    kernels deleted. 3 dispatches: prep, deform_r1(coop), deform_r2(coop).
// ws: xT/out1 8MB | (raw slot unused) | wTg1 | wTg2 | wT61/wT62 | pstats

typedef unsigned int u32;
typedef unsigned short u16;
typedef __attribute__((ext_vector_type(8))) short bf16x8;
typedef __attribute__((ext_vector_type(4))) float floatx4;

#define HW 4096
#define CHW 1048576

static __device__ __forceinline__ float bf2f(u16 u) {
    union { u32 i; float f; } c; c.i = ((u32)u) << 16; return c.f;
}
static __device__ __forceinline__ u16 f2bf(float f) {
    union { float f; u32 i; } c; c.f = f;
    u32 x = c.i;
    return (u16)((x + 0x7FFFu + ((x >> 16) & 1u)) >> 16);   // RNE
}
static __device__ __forceinline__ u32 cvtpk(float a, float b) {
    u32 r;
    asm("v_cvt_pk_bf16_f32 %0, %1, %2" : "=v"(r) : "v"(a), "v"(b));
    return r;
}
// Light barrier: drain LDS ops, sync, do NOT drain vmcnt.
static __device__ __forceinline__ void lbar() {
    __builtin_amdgcn_sched_barrier(0);
    asm volatile("s_waitcnt lgkmcnt(0)" ::: "memory");
    __builtin_amdgcn_s_barrier();
    __builtin_amdgcn_sched_barrier(0);
}
static __device__ __forceinline__ float loadv(const void* p, long i, int f32) {
    return f32 ? ((const float*)p)[i] : bf2f(((const u16*)p)[i]);
}
static __device__ __forceinline__ int sniff_f32(const u32* __restrict__ xw) {
    int cnt = 0;
    #pragma unroll
    for (int s = 0; s < 16; ++s) {
        union { u32 i; float f; } c;
        c.i = xw[s * 131 + 7];
        float a = fabsf(c.f);
        if (a > 1e-8f && a < 1e4f) ++cnt;
    }
    return (cnt >= 8) ? 1 : 0;
}

// ---------------------------------------------------------------------------
// Prep: blocks [0,512) NCHW->NHWC transpose (half-rows); [512,2816) wTg1/2;
// [2816,3104) wT61/2.  (unchanged from v16)
// ---------------------------------------------------------------------------
__global__ __launch_bounds__(256) void k_prep_all(
    const void* __restrict__ x,
    const void* __restrict__ wdc1, const void* __restrict__ wdc2,
    const void* __restrict__ wtm1, const void* __restrict__ wtr1,
    const void* __restrict__ wtm2, const void* __restrict__ wtr2,
    u16* __restrict__ xT, u16* __restrict__ wTg1, u16* __restrict__ wTg2,
    u16* __restrict__ wT61, u16* __restrict__ wT62)
{
    __shared__ u16 T[32 * 258];
    const int f32 = sniff_f32((const u32*)x);
    const int b = blockIdx.x;
    const int tid = threadIdx.x;

    if (b < 512) {                       // ---- NCHW -> NHWC, half-row blocks
        const int n = b >> 7, h = (b >> 1) & 63, half = b & 1;
        const int wbase = half << 5;
        const long sb = (long)n * CHW + (h << 6) + wbase;
        const int cb = tid >> 3;         // 0..31
        const int w0 = (tid & 7) << 2;   // 0,4,...,28
        if (f32) {
            const float* xp = (const float*)x;
            for (int it = 0; it < 8; ++it) {
                int c = (it << 5) + cb;
                float4 a = *(const float4*)(xp + sb + (long)c * HW + w0);
                T[(w0 + 0) * 258 + c] = f2bf(a.x);
                T[(w0 + 1) * 258 + c] = f2bf(a.y);
                T[(w0 + 2) * 258 + c] = f2bf(a.z);
                T[(w0 + 3) * 258 + c] = f2bf(a.w);
            }
        } else {
            const u16* xp = (const u16*)x;
            for (int it = 0; it < 8; ++it) {
                int c = (it << 5) + cb;
                uint2 v = *(const uint2*)(xp + sb + (long)c * HW + w0);
                T[(w0 + 0) * 258 + c] = (u16)(v.x & 0xFFFFu);
                T[(w0 + 1) * 258 + c] = (u16)(v.x >> 16);
                T[(w0 + 2) * 258 + c] = (u16)(v.y & 0xFFFFu);
                T[(w0 + 3) * 258 + c] = (u16)(v.y >> 16);
            }
        }
        __syncthreads();
        const int w = tid >> 3, cq = tid & 7;
        const u32* Tr = (const u32*)T;
        u16* ob = xT + (long)n * CHW + (long)((h << 6) + wbase + w) * 256 + cq * 32;
        #pragma unroll
        for (int s = 0; s < 4; ++s) {
            uint4 o;
            o.x = Tr[129 * w + 16 * cq + 4 * s + 0];
            o.y = Tr[129 * w + 16 * cq + 4 * s + 1];
            o.z = Tr[129 * w + 16 * cq + 4 * s + 2];
            o.w = Tr[129 * w + 16 * cq + 4 * s + 3];
            *(uint4*)&ob[s * 8] = o;
        }
    } else if (b < 2816) {               // ---- deform weights (both rounds)
        const int r2 = (b >= 1664);
        const void* wdc = r2 ? wdc2 : wdc1;
        u16* wTg = r2 ? wTg2 : wTg1;
        int idx2 = (b - (r2 ? 1664 : 512)) * 256 + tid;   // 0..294911
        int cp = idx2 & 15;
        int o  = (idx2 >> 4) & 255;
        int q  = idx2 >> 12;
        int k  = q >> 3;
        int c0 = ((q & 7) << 5) + (cp << 1);
        long s0 = (long)o * 2304 + c0 * 9 + k;
        ((u32*)wTg)[idx2] = cvtpk(loadv(wdc, s0, f32), loadv(wdc, s0 + 9, f32));
    } else {                             // ---- offset-conv weights
        const int r2 = (b >= 2960);
        const void* wtm = r2 ? wtm2 : wtm1;
        const void* wtr = r2 ? wtr2 : wtr1;
        u16* wT6 = r2 ? wT62 : wT61;
        int i = (b - (r2 ? 2960 : 2816)) * 256 + tid;     // 0..36863
        int q  = i >> 9;
        int o  = (i >> 5) & 15;
        int cc = i & 31;
        int k  = q >> 3;
        int c  = ((q & 7) << 5) + cc;
        float v = 0.f;
        if (o < 4)      v = loadv(wtm, (long)o * 2304 + c * 9 + k, f32);
        else if (o < 6) v = loadv(wtr, (long)(o - 4) * 2304 + c * 9 + k, f32);
        wT6[i] = f2bf(v);
    }
}

// ---------------------------------------------------------------------------
// Fused deform + GN (cooperative). grid 256 = (n, h); 1024 thr / 16 waves.
// final_mode=0: out = relu(gn(conv)) stored NHWC u16 (out1).
// final_mode=1: out = relu(gn(conv) + xres) stored NCHW (f32 or bf16).
// ---------------------------------------------------------------------------
__global__ __launch_bounds__(1024, 4) void k_deform_fused(
    const u16* __restrict__ srcT, const u16* __restrict__ wTg,
    const u16* __restrict__ wT6,
    const void* __restrict__ b_tm, const void* __restrict__ b_tr,
    const u32* __restrict__ xw,
    float* __restrict__ pstats,
    const void* __restrict__ gamma, const void* __restrict__ beta,
    const void* __restrict__ xres,
    void* __restrict__ outp,
    const int final_mode)
{
    __shared__ __align__(16) char shm[65536];   // union: red / Sl dbuf / merge / sred
    __shared__ float tl[6 * 64];
    __shared__ int   g_y0[576];
    __shared__ int   g_x0[576];
    __shared__ float g_wy[576];
    __shared__ float g_wx[576];

    const int tid = threadIdx.x;
    const int bid = blockIdx.x;                 // n*64 + h
    const int n = bid >> 6, h = bid & 63;
    const int lane = tid & 63;
    const int quad = lane >> 4;
    const int l16  = lane & 15;
    const int wv   = tid >> 6;                  // 0..15
    const long nbase = (long)n * CHW;
    const u16* sp = srcT + nbase;

    // ---- Stage A: offset conv, 6 out-ch x 64 px (waves 0..7 only) ----
    {
        float (*red)[64][17] = (float (*)[64][17])shm;
        if (wv < 8) {
            floatx4 acc6[4];
            #pragma unroll
            for (int j = 0; j < 4; ++j) acc6[j] = (floatx4){0.f, 0.f, 0.f, 0.f};
            for (int qi = 0; qi < 9; ++qi) {
                const int q = wv * 9 + qi;
                const int k = q >> 3, cb = q & 7;
                const int ky = k / 3, kx = k % 3;
                const int row = h + ky - 1;
                const bool rv = (row >= 0) && (row < 64);
                bf16x8 av = *(const bf16x8*)&wT6[(((q << 4) + l16) << 5) + (quad << 3)];
                #pragma unroll
                for (int j = 0; j < 4; ++j) {
                    int psrc = (j << 4) + l16 + kx - 1;
                    bf16x8 bv = {0, 0, 0, 0, 0, 0, 0, 0};
                    if (rv && psrc >= 0 && psrc < 64)
                        bv = *(const bf16x8*)&sp[(((long)(row << 6) + psrc) << 8) + (cb << 5) + (quad << 3)];
                    acc6[j] = __builtin_amdgcn_mfma_f32_16x16x32_bf16(av, bv, acc6[j], 0, 0, 0);
                }
            }
            #pragma unroll
            for (int j = 0; j < 4; ++j)
                #pragma unroll
                for (int r = 0; r < 4; ++r)
                    red[wv][(j << 4) + l16][(quad << 2) + r] = acc6[j][r];
        }
        __syncthreads();
        if (tid < 384) {
            const int o = tid >> 6, px = tid & 63;
            float s = 0.f;
            #pragma unroll
            for (int v = 0; v < 8; ++v) s += red[v][px][o];
            const int f32 = sniff_f32(xw);
            float bias = (o < 4) ? loadv(b_tm, o, f32) : loadv(b_tr, o - 4, f32);
            tl[o * 64 + px] = s + bias;
        }
        __syncthreads();
    }

    // ---- Stage B: geometry for 9 taps x 64 px ----
    if (tid < 576) {
        int i = tid;
        int k = i >> 6, ww2 = i & 63;
        float m00 = tl[ww2],        m01 = tl[64 + ww2];
        float m10 = tl[128 + ww2],  m11 = tl[192 + ww2];
        float tr0 = tl[256 + ww2],  tr1 = tl[320 + ww2];
        float ry = (float)(k / 3) - 1.f;
        float rx = (float)(k % 3) - 1.f;
        float dy = m00 * ry + m01 * rx - ry + tr0;
        float dx = m10 * ry + m11 * rx - rx + tr1;
        float py = (float)h + ry + dy;
        float px = (float)ww2 + rx + dx;
        float y0f = floorf(py), x0f = floorf(px);
        g_y0[i] = (int)y0f; g_x0[i] = (int)x0f;
        g_wy[i] = py - y0f; g_wx[i] = px - x0f;
    }
    __syncthreads();

    // ---- Stage C: 9-tap loop, K-split, dist-2 weight prefetch (v16) ----
    const int px   = tid >> 4;     // 0..63  (PUB role)
    const int slot = tid & 15;     // 0..15
    const int kh   = wv >> 3;      // K-half
    const int o0   = (wv & 7) << 5;  // 32 out-ch per wave
    const u32 xw_s = (u32)((px  & 7) << 2);
    const u32 xsw  = (u32)((l16 & 7) << 2);
    const u32 q4x  = (u32)(quad << 2);
    const u32 kh64 = (u32)(kh << 6);

    u32* Sl = (u32*)shm;           // [2][64 px][128 u32], swizzled

    floatx4 acc[2][4];
    #pragma unroll
    for (int a = 0; a < 2; ++a)
        #pragma unroll
        for (int g = 0; g < 4; ++g) acc[a][g] = (floatx4){0.f, 0.f, 0.f, 0.f};

    const int wlane = ((o0 + l16) << 5) + (quad << 3);
    const u16* wk = wTg + (kh << 15);   // + 65536 u16 per tap

    u32 o00, o01, o10, o11;             // corner byte offsets
    float cw00, cw01, cw10, cw11;
    const char* spb = (const char*)sp + (slot << 4);

    auto mkptr = [&](int k) {
        int gi = (k << 6) + px;
        int y0 = g_y0[gi], x0 = g_x0[gi];
        int yc0 = min(max(y0, 0), 63),     yc1 = min(max(y0 + 1, 0), 63);
        int xc0 = min(max(x0, 0), 63),     xc1 = min(max(x0 + 1, 0), 63);
        o00 = (u32)(((yc0 << 6) + xc0) << 9);
        o01 = (u32)(((yc0 << 6) + xc1) << 9);
        o10 = (u32)(((yc1 << 6) + xc0) << 9);
        o11 = (u32)(((yc1 << 6) + xc1) << 9);
    };
    auto mkcw = [&](int k) {
        int gi = (k << 6) + px;
        int y0 = g_y0[gi], x0 = g_x0[gi];
        float wy1 = g_wy[gi], wx1 = g_wx[gi];
        float wy0 = 1.f - wy1, wx0 = 1.f - wx1;
        bool yv0 = (y0 >= 0) && (y0 < 64);
        bool yv1 = (y0 >= -1) && (y0 < 63);
        bool xv0 = (x0 >= 0) && (x0 < 64);
        bool xv1 = (x0 >= -1) && (x0 < 63);
        cw00 = (yv0 && xv0) ? wy0 * wx0 : 0.f;
        cw01 = (yv0 && xv1) ? wy0 * wx1 : 0.f;
        cw10 = (yv1 && xv0) ? wy1 * wx0 : 0.f;
        cw11 = (yv1 && xv1) ? wy1 * wx1 : 0.f;
    };

    uint4 GA, GB, GC, GD, HA, HB, HC, HD;
    auto GATHER = [&]() {
        GA = *(const uint4*)(spb + o00);  HA = *(const uint4*)(spb + o00 + 256);
        GB = *(const uint4*)(spb + o01);  HB = *(const uint4*)(spb + o01 + 256);
        GC = *(const uint4*)(spb + o10);  HC = *(const uint4*)(spb + o10 + 256);
        GD = *(const uint4*)(spb + o11);  HD = *(const uint4*)(spb + o11 + 256);
    };

    bf16x8 W0[4], W1[4];    // 4-slot rotation, dist-2 (4 sub-steps/tap)

#define BIL(a, b, c, d) cvtpk( \
    fmaf(cw00, bf2f((u16)(a)), fmaf(cw01, bf2f((u16)(b)), \
    fmaf(cw10, bf2f((u16)(c)), cw11 * bf2f((u16)(d))))), \
    fmaf(cw00, bf2f((u16)((a) >> 16)), fmaf(cw01, bf2f((u16)((b) >> 16)), \
    fmaf(cw10, bf2f((u16)((c) >> 16)), cw11 * bf2f((u16)((d) >> 16))))))

    // prologue: gathers tap 0; weight slices t=0,1
    mkptr(0); GATHER();
    W0[0] = *(const bf16x8*)(wk + wlane);
    W1[0] = *(const bf16x8*)(wk + wlane + 512);
    W0[1] = *(const bf16x8*)(wk + 8192 + wlane);
    W1[1] = *(const bf16x8*)(wk + 8192 + wlane + 512);

    for (int k = 0; k < 9; ++k) {
        const int buf = k & 1;
        // PUB: bilinear-combine tap k, store swizzled
        mkcw(k);
        uint4 v0 = make_uint4(BIL(GA.x, GB.x, GC.x, GD.x), BIL(GA.y, GB.y, GC.y, GD.y),
                              BIL(GA.z, GB.z, GC.z, GD.z), BIL(GA.w, GB.w, GC.w, GD.w));
        uint4 v1 = make_uint4(BIL(HA.x, HB.x, HC.x, HD.x), BIL(HA.y, HB.y, HC.y, HD.y),
                              BIL(HA.z, HB.z, HC.z, HD.z), BIL(HA.w, HB.w, HC.w, HD.w));
        u32* wp = &Sl[((u32)(buf << 13)) + ((u32)(px << 7)) + (((u32)(slot << 2)) ^ xw_s)];
        *(uint4*)wp = v0;
        *(uint4*)(wp + 64) = v1;
        // issue tap k+1 gathers (in flight across barrier + MFMA phase)
        if (k < 8) { mkptr(k + 1); GATHER(); }
        lbar();
        // MFMA phase: 4 barrier-free sub-steps over this wave's K-half
        const u32* sb = &Sl[(u32)(buf << 13)];
        #pragma unroll
        for (int c = 0; c < 4; ++c) {
            const u32 offc = (((kh64 + (u32)(c << 4))) | q4x) ^ xsw;
            bf16x8 b0 = *(const bf16x8*)(sb + ((u32)(( 0 + l16) << 7)) + offc);
            bf16x8 b1 = *(const bf16x8*)(sb + ((u32)((16 + l16) << 7)) + offc);
            bf16x8 b2 = *(const bf16x8*)(sb + ((u32)((32 + l16) << 7)) + offc);
            bf16x8 b3 = *(const bf16x8*)(sb + ((u32)((48 + l16) << 7)) + offc);
            if (k < 8 || c < 2) {               // load slice t+2 (t = k*4+c)
                const int tc = c + 2;
                const u16* wb = wk + ((tc & 3) + ((tc >> 2) << 3)) * 8192;
                W0[tc & 3] = *(const bf16x8*)(wb + wlane);
                W1[tc & 3] = *(const bf16x8*)(wb + wlane + 512);
            }
            acc[0][0] = __builtin_amdgcn_mfma_f32_16x16x32_bf16(W0[c], b0, acc[0][0], 0, 0, 0);
            acc[0][1] = __builtin_amdgcn_mfma_f32_16x16x32_bf16(W0[c], b1, acc[0][1], 0, 0, 0);
            acc[0][2] = __builtin_amdgcn_mfma_f32_16x16x32_bf16(W0[c], b2, acc[0][2], 0, 0, 0);
            acc[0][3] = __builtin_amdgcn_mfma_f32_16x16x32_bf16(W0[c], b3, acc[0][3], 0, 0, 0);
            acc[1][0] = __builtin_amdgcn_mfma_f32_16x16x32_bf16(W1[c], b0, acc[1][0], 0, 0, 0);
            acc[1][1] = __builtin_amdgcn_mfma_f32_16x16x32_bf16(W1[c], b1, acc[1][1], 0, 0, 0);
            acc[1][2] = __builtin_amdgcn_mfma_f32_16x16x32_bf16(W1[c], b2, acc[1][2], 0, 0, 0);
            acc[1][3] = __builtin_amdgcn_mfma_f32_16x16x32_bf16(W1[c], b3, acc[1][3], 0, 0, 0);
        }
        wk += 65536;
    }
#undef BIL

    // ---- K-half merge: kh=1 waves dump acc, kh=0 waves add ----
    __syncthreads();
    {
        float* ms = (float*)shm;
        if (kh == 1) {
            #pragma unroll
            for (int a = 0; a < 2; ++a)
                #pragma unroll
                for (int g = 0; g < 4; ++g)
                    *(floatx4*)&ms[((((wv & 7) << 3) + (a << 2) + g) << 8) + (lane << 2)] = acc[a][g];
        }
        __syncthreads();
        if (kh == 0) {
            #pragma unroll
            for (int a = 0; a < 2; ++a)
                #pragma unroll
                for (int g = 0; g < 4; ++g) {
                    floatx4 t = *(const floatx4*)&ms[((((wv & 7) << 3) + (a << 2) + g) << 8) + (lane << 2)];
                    acc[a][g] += t;
                }
        }
    }

    // ---- Stage D: GN partials (kh=0 waves) ----
    if (kh == 0) {
        #pragma unroll
        for (int a = 0; a < 2; ++a) {
            float s1 = 0.f, s2 = 0.f;
            #pragma unroll
            for (int g = 0; g < 4; ++g)
                #pragma unroll
                for (int r = 0; r < 4; ++r) {
                    float v = acc[a][g][r];
                    s1 += v; s2 += v * v;
                }
            #pragma unroll
            for (int off = 1; off <= 16; off <<= 1) {
                s1 += __shfl_xor(s1, off, 64);
                s2 += __shfl_xor(s2, off, 64);
            }
            if ((lane & 31) == 0) {
                int gg = (o0 >> 3) + (a << 1) + (lane >> 5);
                pstats[((long)bid << 6) + (gg << 1)]     = s1;
                pstats[((long)bid << 6) + (gg << 1) + 1] = s2;
            }
        }
    }

    // ---- grid-wide sync: pstats complete everywhere ----
    __threadfence();
    cg::this_grid().sync();

    // ---- reduce pstats for this n -> tl[0..63] (all threads) ----
    {
        float* sred = (float*)shm;           // 16 x 64 floats
        const int v = tid & 63, part = tid >> 6;
        float a = 0.f;
        #pragma unroll
        for (int j = part * 4; j < part * 4 + 4; ++j)
            a += pstats[(((long)n * 64 + j) << 6) + v];
        sred[part * 64 + v] = a;
        __syncthreads();
        if (tid < 64) {
            float s = 0.f;
            #pragma unroll
            for (int p = 0; p < 16; ++p) s += sred[p * 64 + tid];
            tl[tid] = s;
        }
        __syncthreads();
    }

    // ---- fused normalize + store (kh=0 waves hold full acc) ----
    if (kh == 0) {
        const int f32 = sniff_f32(xw);
        #pragma unroll
        for (int a2 = 0; a2 < 2; ++a2) {
            const int ob = o0 + (a2 << 4) + (quad << 2);   // 4 consecutive ch
            const int g = ob >> 3;
            float mean = tl[g * 2] * (1.f / 32768.f);
            float var  = tl[g * 2 + 1] * (1.f / 32768.f) - mean * mean;
            float rstd = rsqrtf(var + 1e-5f);
            float ga[4], be[4];
            #pragma unroll
            for (int r = 0; r < 4; ++r) {
                ga[r] = loadv(gamma, ob + r, f32) * rstd;
                be[r] = loadv(beta,  ob + r, f32) - mean * ga[r];
            }
            if (final_mode == 0) {
                // relu(gn(conv)) -> NHWC u16
                u16* rb = (u16*)outp + nbase + ((long)h << 14);
                #pragma unroll
                for (int g2 = 0; g2 < 4; ++g2) {
                    int pxe = (g2 << 4) + l16;
                    float v0 = fmaxf(fmaf(acc[a2][g2][0], ga[0], be[0]), 0.f);
                    float v1 = fmaxf(fmaf(acc[a2][g2][1], ga[1], be[1]), 0.f);
                    float v2 = fmaxf(fmaf(acc[a2][g2][2], ga[2], be[2]), 0.f);
                    float v3 = fmaxf(fmaf(acc[a2][g2][3], ga[3], be[3]), 0.f);
                    *(uint2*)&rb[((long)pxe << 8) + ob] =
                        make_uint2(cvtpk(v0, v1), cvtpk(v2, v3));
                }
            } else {
                // relu(gn(conv) + xres) -> NCHW (f32 or bf16)
                #pragma unroll
                for (int r = 0; r < 4; ++r) {
                    const long base = nbase + ((long)(ob + r) << 12) + (h << 6);
                    #pragma unroll
                    for (int g2 = 0; g2 < 4; ++g2) {
                        int pxe = (g2 << 4) + l16;
                        float v = fmaf(acc[a2][g2][r], ga[r], be[r])
                                + loadv(xres, base + pxe, f32);
                        v = fmaxf(v, 0.f);
                        if (f32) ((float*)outp)[base + pxe] = v;
                        else     ((u16*)outp)[base + pxe] = f2bf(v);
                    }
                }
            }
        }
    }
}

extern "C" void kernel_launch(void* const* d_in, const int* in_sizes, int n_in,
                              void* d_out, int out_size, void* d_ws, size_t ws_size,
                              hipStream_t stream) {
    const void* x     = d_in[0];
    const void* w_tm1 = d_in[1];
    const void* b_tm1 = d_in[2];
    const void* w_tr1 = d_in[3];
    const void* b_tr1 = d_in[4];
    const void* w_dc1 = d_in[5];
    const void* g1    = d_in[6];
    const void* be1   = d_in[7];
    const void* w_tm2 = d_in[8];
    const void* b_tm2 = d_in[9];
    const void* w_tr2 = d_in[10];
    const void* b_tr2 = d_in[11];
    const void* w_dc2 = d_in[12];
    const void* g2    = d_in[13];
    const void* be2   = d_in[14];

    char* wsb = (char*)d_ws;
    u16*   xT     = (u16*)wsb;                       // 8,388,608 (alias out1)
    u16*   wTg1   = (u16*)(wsb + 16777216);          // 1,179,648
    u16*   wTg2   = (u16*)(wsb + 17956864);          // 1,179,648
    u16*   wT61   = (u16*)(wsb + 19136512);          //    73,728
    u16*   wT62   = (u16*)(wsb + 19210240);          //    73,728
    float* pstats = (float*)(wsb + 19283968);        //   131,072
    u16*   out1   = xT;
    const u32* xw = (const u32*)x;

    k_prep_all<<<3104, 256, 0, stream>>>(x, w_dc1, w_dc2, w_tm1, w_tr1, w_tm2, w_tr2,
                                         xT, wTg1, wTg2, wT61, wT62);

    // ---- round 1 (cooperative: fused GN+relu -> out1 NHWC) ----
    {
        const u16* srcT = xT;  const u16* wTg = wTg1;  const u16* wT6 = wT61;
        const void* btm = b_tm1; const void* btr = b_tr1;
        const u32* xwv = xw; float* pst = pstats;
        const void* gam = g1; const void* bet = be1;
        const void* xr = nullptr; void* op = (void*)out1; int fm = 0;
        void* args[] = {&srcT, &wTg, &wT6, &btm, &btr, &xwv, &pst,
                        &gam, &bet, &xr, &op, &fm};
        hipLaunchCooperativeKernel((const void*)k_deform_fused,
                                   dim3(256), dim3(1024), args, 0, stream);
    }
    // ---- round 2 (cooperative: fused GN+residual+relu -> d_out NCHW) ----
    {
        const u16* srcT = out1; const u16* wTg = wTg2; const u16* wT6 = wT62;
        const void* btm = b_tm2; const void* btr = b_tr2;
        const u32* xwv = xw; float* pst = pstats;
        const void* gam = g2; const void* bet = be2;
        const void* xr = x; void* op = d_out; int fm = 1;
        void* args[] = {&srcT, &wTg, &wT6, &btm, &btr, &xwv, &pst,
                        &gam, &bet, &xr, &op, &fm};
        hipLaunchCooperativeKernel((const void*)k_deform_fused,
                                   dim3(256), dim3(1024), args, 0, stream);
    }
}

// Round 10
// 208.930 us; speedup vs baseline: 2.0854x; 2.0854x over previous
//
#include <hip/hip_runtime.h>

// v19: exact v16 (best verified: 211.6 us; v17 full-tap prefetch and v18
// cooperative fusion both REVERTED as regressions) + XCD-aware block swizzle
// in k_deform: dispatch d -> logical bid=(d&7)*32+(d>>3), giving each XCD a
// contiguous 32-row half-image -> gather rows + weight stream become
// XCD-local L2 hits (working set ~1.7MB << 4MB/XCD L2).
// 5 dispatches. ws: xT/out1 8MB | raw 8MB | wTg1 1.18MB | wTg2 1.18MB |
//   wT61/wT62 72KB | pstats 64KB

typedef unsigned int u32;
typedef unsigned short u16;
typedef __attribute__((ext_vector_type(8))) short bf16x8;
typedef __attribute__((ext_vector_type(4))) float floatx4;

#define HW 4096
#define CHW 1048576

static __device__ __forceinline__ float bf2f(u16 u) {
    union { u32 i; float f; } c; c.i = ((u32)u) << 16; return c.f;
}
static __device__ __forceinline__ u16 f2bf(float f) {
    union { float f; u32 i; } c; c.f = f;
    u32 x = c.i;
    return (u16)((x + 0x7FFFu + ((x >> 16) & 1u)) >> 16);   // RNE
}
static __device__ __forceinline__ u32 cvtpk(float a, float b) {
    u32 r;
    asm("v_cvt_pk_bf16_f32 %0, %1, %2" : "=v"(r) : "v"(a), "v"(b));
    return r;
}
// Light barrier: drain LDS ops, sync, do NOT drain vmcnt.
static __device__ __forceinline__ void lbar() {
    __builtin_amdgcn_sched_barrier(0);
    asm volatile("s_waitcnt lgkmcnt(0)" ::: "memory");
    __builtin_amdgcn_s_barrier();
    __builtin_amdgcn_sched_barrier(0);
}
static __device__ __forceinline__ float loadv(const void* p, long i, int f32) {
    return f32 ? ((const float*)p)[i] : bf2f(((const u16*)p)[i]);
}
static __device__ __forceinline__ int sniff_f32(const u32* __restrict__ xw) {
    int cnt = 0;
    #pragma unroll
    for (int s = 0; s < 16; ++s) {
        union { u32 i; float f; } c;
        c.i = xw[s * 131 + 7];
        float a = fabsf(c.f);
        if (a > 1e-8f && a < 1e4f) ++cnt;
    }
    return (cnt >= 8) ? 1 : 0;
}

// ---------------------------------------------------------------------------
// Prep: blocks [0,512) NCHW->NHWC transpose (half-rows); [512,2816) wTg1/2;
// [2816,3104) wT61/2.
// ---------------------------------------------------------------------------
__global__ __launch_bounds__(256) void k_prep_all(
    const void* __restrict__ x,
    const void* __restrict__ wdc1, const void* __restrict__ wdc2,
    const void* __restrict__ wtm1, const void* __restrict__ wtr1,
    const void* __restrict__ wtm2, const void* __restrict__ wtr2,
    u16* __restrict__ xT, u16* __restrict__ wTg1, u16* __restrict__ wTg2,
    u16* __restrict__ wT61, u16* __restrict__ wT62)
{
    __shared__ u16 T[32 * 258];
    const int f32 = sniff_f32((const u32*)x);
    const int b = blockIdx.x;
    const int tid = threadIdx.x;

    if (b < 512) {                       // ---- NCHW -> NHWC, half-row blocks
        const int n = b >> 7, h = (b >> 1) & 63, half = b & 1;
        const int wbase = half << 5;
        const long sb = (long)n * CHW + (h << 6) + wbase;
        const int cb = tid >> 3;         // 0..31
        const int w0 = (tid & 7) << 2;   // 0,4,...,28
        if (f32) {
            const float* xp = (const float*)x;
            for (int it = 0; it < 8; ++it) {
                int c = (it << 5) + cb;
                float4 a = *(const float4*)(xp + sb + (long)c * HW + w0);
                T[(w0 + 0) * 258 + c] = f2bf(a.x);
                T[(w0 + 1) * 258 + c] = f2bf(a.y);
                T[(w0 + 2) * 258 + c] = f2bf(a.z);
                T[(w0 + 3) * 258 + c] = f2bf(a.w);
            }
        } else {
            const u16* xp = (const u16*)x;
            for (int it = 0; it < 8; ++it) {
                int c = (it << 5) + cb;
                uint2 v = *(const uint2*)(xp + sb + (long)c * HW + w0);
                T[(w0 + 0) * 258 + c] = (u16)(v.x & 0xFFFFu);
                T[(w0 + 1) * 258 + c] = (u16)(v.x >> 16);
                T[(w0 + 2) * 258 + c] = (u16)(v.y & 0xFFFFu);
                T[(w0 + 3) * 258 + c] = (u16)(v.y >> 16);
            }
        }
        __syncthreads();
        const int w = tid >> 3, cq = tid & 7;
        const u32* Tr = (const u32*)T;
        u16* ob = xT + (long)n * CHW + (long)((h << 6) + wbase + w) * 256 + cq * 32;
        #pragma unroll
        for (int s = 0; s < 4; ++s) {
            uint4 o;
            o.x = Tr[129 * w + 16 * cq + 4 * s + 0];
            o.y = Tr[129 * w + 16 * cq + 4 * s + 1];
            o.z = Tr[129 * w + 16 * cq + 4 * s + 2];
            o.w = Tr[129 * w + 16 * cq + 4 * s + 3];
            *(uint4*)&ob[s * 8] = o;
        }
    } else if (b < 2816) {               // ---- deform weights (both rounds)
        const int r2 = (b >= 1664);
        const void* wdc = r2 ? wdc2 : wdc1;
        u16* wTg = r2 ? wTg2 : wTg1;
        int idx2 = (b - (r2 ? 1664 : 512)) * 256 + tid;   // 0..294911
        int cp = idx2 & 15;
        int o  = (idx2 >> 4) & 255;
        int q  = idx2 >> 12;
        int k  = q >> 3;
        int c0 = ((q & 7) << 5) + (cp << 1);
        long s0 = (long)o * 2304 + c0 * 9 + k;
        ((u32*)wTg)[idx2] = cvtpk(loadv(wdc, s0, f32), loadv(wdc, s0 + 9, f32));
    } else {                             // ---- offset-conv weights
        const int r2 = (b >= 2960);
        const void* wtm = r2 ? wtm2 : wtm1;
        const void* wtr = r2 ? wtr2 : wtr1;
        u16* wT6 = r2 ? wT62 : wT61;
        int i = (b - (r2 ? 2960 : 2816)) * 256 + tid;     // 0..36863
        int q  = i >> 9;
        int o  = (i >> 5) & 15;
        int cc = i & 31;
        int k  = q >> 3;
        int c  = ((q & 7) << 5) + cc;
        float v = 0.f;
        if (o < 4)      v = loadv(wtm, (long)o * 2304 + c * 9 + k, f32);
        else if (o < 6) v = loadv(wtr, (long)(o - 4) * 2304 + c * 9 + k, f32);
        wT6[i] = f2bf(v);
    }
}

// ---------------------------------------------------------------------------
// Mega deform, full-row blocks: grid 256 = (n, h); 1024 threads / 16 waves.
// nhwc flag: raw stored NHWC (round 1) or NCHW (round 2).
// XCD swizzle: dispatch d -> logical bid = (d&7)*32 + (d>>3) (bijective,
// 256%8==0) so each XCD works a contiguous 32-row half-image.
// ---------------------------------------------------------------------------
__global__ __launch_bounds__(1024, 4) void k_deform(
    const u16* __restrict__ srcT, const u16* __restrict__ wTg,
    const u16* __restrict__ wT6,
    const void* __restrict__ b_tm, const void* __restrict__ b_tr,
    const u32* __restrict__ xw,
    u16* __restrict__ raw, float* __restrict__ pstats, const int nhwc)
{
    __shared__ __align__(16) char shm[65536];   // union: red / Sl dbuf / acc-merge
    __shared__ float tl[6 * 64];
    __shared__ int   g_y0[576];
    __shared__ int   g_x0[576];
    __shared__ float g_wy[576];
    __shared__ float g_wx[576];

    const int tid = threadIdx.x;
    const int d = blockIdx.x;
    const int bid = ((d & 7) << 5) | (d >> 3);  // XCD-contiguous logical block
    const int n = bid >> 6, h = bid & 63;
    const int lane = tid & 63;
    const int quad = lane >> 4;
    const int l16  = lane & 15;
    const int wv   = tid >> 6;                  // 0..15
    const long nbase = (long)n * CHW;
    const u16* sp = srcT + nbase;

    // ---- Stage A: offset conv, 6 out-ch x 64 px (waves 0..7 only) ----
    {
        float (*red)[64][17] = (float (*)[64][17])shm;
        if (wv < 8) {
            floatx4 acc6[4];
            #pragma unroll
            for (int j = 0; j < 4; ++j) acc6[j] = (floatx4){0.f, 0.f, 0.f, 0.f};
            for (int qi = 0; qi < 9; ++qi) {
                const int q = wv * 9 + qi;
                const int k = q >> 3, cb = q & 7;
                const int ky = k / 3, kx = k % 3;
                const int row = h + ky - 1;
                const bool rv = (row >= 0) && (row < 64);
                bf16x8 av = *(const bf16x8*)&wT6[(((q << 4) + l16) << 5) + (quad << 3)];
                #pragma unroll
                for (int j = 0; j < 4; ++j) {
                    int psrc = (j << 4) + l16 + kx - 1;
                    bf16x8 bv = {0, 0, 0, 0, 0, 0, 0, 0};
                    if (rv && psrc >= 0 && psrc < 64)
                        bv = *(const bf16x8*)&sp[(((long)(row << 6) + psrc) << 8) + (cb << 5) + (quad << 3)];
                    acc6[j] = __builtin_amdgcn_mfma_f32_16x16x32_bf16(av, bv, acc6[j], 0, 0, 0);
                }
            }
            #pragma unroll
            for (int j = 0; j < 4; ++j)
                #pragma unroll
                for (int r = 0; r < 4; ++r)
                    red[wv][(j << 4) + l16][(quad << 2) + r] = acc6[j][r];
        }
        __syncthreads();
        if (tid < 384) {
            const int o = tid >> 6, px = tid & 63;
            float s = 0.f;
            #pragma unroll
            for (int v = 0; v < 8; ++v) s += red[v][px][o];
            const int f32 = sniff_f32(xw);
            float bias = (o < 4) ? loadv(b_tm, o, f32) : loadv(b_tr, o - 4, f32);
            tl[o * 64 + px] = s + bias;
        }
        __syncthreads();
    }

    // ---- Stage B: geometry for 9 taps x 64 px ----
    if (tid < 576) {
        int i = tid;
        int k = i >> 6, ww2 = i & 63;
        float m00 = tl[ww2],        m01 = tl[64 + ww2];
        float m10 = tl[128 + ww2],  m11 = tl[192 + ww2];
        float tr0 = tl[256 + ww2],  tr1 = tl[320 + ww2];
        float ry = (float)(k / 3) - 1.f;
        float rx = (float)(k % 3) - 1.f;
        float dy = m00 * ry + m01 * rx - ry + tr0;
        float dx = m10 * ry + m11 * rx - rx + tr1;
        float py = (float)h + ry + dy;
        float px = (float)ww2 + rx + dx;
        float y0f = floorf(py), x0f = floorf(px);
        g_y0[i] = (int)y0f; g_x0[i] = (int)x0f;
        g_wy[i] = py - y0f; g_wx[i] = px - x0f;
    }
    __syncthreads();

    // ---- Stage C: 9-tap loop, K-split, dist-2 weight prefetch ----
    const int px   = tid >> 4;     // 0..63  (PUB role)
    const int slot = tid & 15;     // 0..15
    const int kh   = wv >> 3;      // K-half
    const int o0   = (wv & 7) << 5;  // 32 out-ch per wave
    const u32 xw_s = (u32)((px  & 7) << 2);
    const u32 xsw  = (u32)((l16 & 7) << 2);
    const u32 q4x  = (u32)(quad << 2);
    const u32 kh64 = (u32)(kh << 6);

    u32* Sl = (u32*)shm;           // [2][64 px][128 u32], swizzled

    floatx4 acc[2][4];
    #pragma unroll
    for (int a = 0; a < 2; ++a)
        #pragma unroll
        for (int g = 0; g < 4; ++g) acc[a][g] = (floatx4){0.f, 0.f, 0.f, 0.f};

    const int wlane = ((o0 + l16) << 5) + (quad << 3);
    const u16* wk = wTg + (kh << 15);   // + 65536 u16 per tap

    u32 o00, o01, o10, o11;             // corner byte offsets
    float cw00, cw01, cw10, cw11;
    const char* spb = (const char*)sp + (slot << 4);

    auto mkptr = [&](int k) {
        int gi = (k << 6) + px;
        int y0 = g_y0[gi], x0 = g_x0[gi];
        int yc0 = min(max(y0, 0), 63),     yc1 = min(max(y0 + 1, 0), 63);
        int xc0 = min(max(x0, 0), 63),     xc1 = min(max(x0 + 1, 0), 63);
        o00 = (u32)(((yc0 << 6) + xc0) << 9);
        o01 = (u32)(((yc0 << 6) + xc1) << 9);
        o10 = (u32)(((yc1 << 6) + xc0) << 9);
        o11 = (u32)(((yc1 << 6) + xc1) << 9);
    };
    auto mkcw = [&](int k) {
        int gi = (k << 6) + px;
        int y0 = g_y0[gi], x0 = g_x0[gi];
        float wy1 = g_wy[gi], wx1 = g_wx[gi];
        float wy0 = 1.f - wy1, wx0 = 1.f - wx1;
        bool yv0 = (y0 >= 0) && (y0 < 64);
        bool yv1 = (y0 >= -1) && (y0 < 63);
        bool xv0 = (x0 >= 0) && (x0 < 64);
        bool xv1 = (x0 >= -1) && (x0 < 63);
        cw00 = (yv0 && xv0) ? wy0 * wx0 : 0.f;
        cw01 = (yv0 && xv1) ? wy0 * wx1 : 0.f;
        cw10 = (yv1 && xv0) ? wy1 * wx0 : 0.f;
        cw11 = (yv1 && xv1) ? wy1 * wx1 : 0.f;
    };

    uint4 GA, GB, GC, GD, HA, HB, HC, HD;
    auto GATHER = [&]() {
        GA = *(const uint4*)(spb + o00);  HA = *(const uint4*)(spb + o00 + 256);
        GB = *(const uint4*)(spb + o01);  HB = *(const uint4*)(spb + o01 + 256);
        GC = *(const uint4*)(spb + o10);  HC = *(const uint4*)(spb + o10 + 256);
        GD = *(const uint4*)(spb + o11);  HD = *(const uint4*)(spb + o11 + 256);
    };

    bf16x8 W0[4], W1[4];    // 4-slot rotation, dist-2 (4 sub-steps/tap)

#define BIL(a, b, c, d) cvtpk( \
    fmaf(cw00, bf2f((u16)(a)), fmaf(cw01, bf2f((u16)(b)), \
    fmaf(cw10, bf2f((u16)(c)), cw11 * bf2f((u16)(d))))), \
    fmaf(cw00, bf2f((u16)((a) >> 16)), fmaf(cw01, bf2f((u16)((b) >> 16)), \
    fmaf(cw10, bf2f((u16)((c) >> 16)), cw11 * bf2f((u16)((d) >> 16))))))

    // prologue: gathers tap 0; weight slices t=0,1
    mkptr(0); GATHER();
    W0[0] = *(const bf16x8*)(wk + wlane);
    W1[0] = *(const bf16x8*)(wk + wlane + 512);
    W0[1] = *(const bf16x8*)(wk + 8192 + wlane);
    W1[1] = *(const bf16x8*)(wk + 8192 + wlane + 512);

    for (int k = 0; k < 9; ++k) {
        const int buf = k & 1;
        // PUB: bilinear-combine tap k, store swizzled
        mkcw(k);
        uint4 v0 = make_uint4(BIL(GA.x, GB.x, GC.x, GD.x), BIL(GA.y, GB.y, GC.y, GD.y),
                              BIL(GA.z, GB.z, GC.z, GD.z), BIL(GA.w, GB.w, GC.w, GD.w));
        uint4 v1 = make_uint4(BIL(HA.x, HB.x, HC.x, HD.x), BIL(HA.y, HB.y, HC.y, HD.y),
                              BIL(HA.z, HB.z, HC.z, HD.z), BIL(HA.w, HB.w, HC.w, HD.w));
        u32* wp = &Sl[((u32)(buf << 13)) + ((u32)(px << 7)) + (((u32)(slot << 2)) ^ xw_s)];
        *(uint4*)wp = v0;
        *(uint4*)(wp + 64) = v1;
        // issue tap k+1 gathers (in flight across barrier + MFMA phase)
        if (k < 8) { mkptr(k + 1); GATHER(); }
        lbar();
        // MFMA phase: 4 barrier-free sub-steps over this wave's K-half
        const u32* sb = &Sl[(u32)(buf << 13)];
        #pragma unroll
        for (int c = 0; c < 4; ++c) {
            const u32 offc = (((kh64 + (u32)(c << 4))) | q4x) ^ xsw;
            bf16x8 b0 = *(const bf16x8*)(sb + ((u32)(( 0 + l16) << 7)) + offc);
            bf16x8 b1 = *(const bf16x8*)(sb + ((u32)((16 + l16) << 7)) + offc);
            bf16x8 b2 = *(const bf16x8*)(sb + ((u32)((32 + l16) << 7)) + offc);
            bf16x8 b3 = *(const bf16x8*)(sb + ((u32)((48 + l16) << 7)) + offc);
            if (k < 8 || c < 2) {               // load slice t+2 (t = k*4+c)
                const int tc = c + 2;
                const u16* wb = wk + ((tc & 3) + ((tc >> 2) << 3)) * 8192;
                W0[tc & 3] = *(const bf16x8*)(wb + wlane);
                W1[tc & 3] = *(const bf16x8*)(wb + wlane + 512);
            }
            acc[0][0] = __builtin_amdgcn_mfma_f32_16x16x32_bf16(W0[c], b0, acc[0][0], 0, 0, 0);
            acc[0][1] = __builtin_amdgcn_mfma_f32_16x16x32_bf16(W0[c], b1, acc[0][1], 0, 0, 0);
            acc[0][2] = __builtin_amdgcn_mfma_f32_16x16x32_bf16(W0[c], b2, acc[0][2], 0, 0, 0);
            acc[0][3] = __builtin_amdgcn_mfma_f32_16x16x32_bf16(W0[c], b3, acc[0][3], 0, 0, 0);
            acc[1][0] = __builtin_amdgcn_mfma_f32_16x16x32_bf16(W1[c], b0, acc[1][0], 0, 0, 0);
            acc[1][1] = __builtin_amdgcn_mfma_f32_16x16x32_bf16(W1[c], b1, acc[1][1], 0, 0, 0);
            acc[1][2] = __builtin_amdgcn_mfma_f32_16x16x32_bf16(W1[c], b2, acc[1][2], 0, 0, 0);
            acc[1][3] = __builtin_amdgcn_mfma_f32_16x16x32_bf16(W1[c], b3, acc[1][3], 0, 0, 0);
        }
        wk += 65536;
    }
#undef BIL

    // ---- K-half merge: kh=1 waves dump acc, kh=0 waves add ----
    __syncthreads();
    {
        float* ms = (float*)shm;
        if (kh == 1) {
            #pragma unroll
            for (int a = 0; a < 2; ++a)
                #pragma unroll
                for (int g = 0; g < 4; ++g)
                    *(floatx4*)&ms[((((wv & 7) << 3) + (a << 2) + g) << 8) + (lane << 2)] = acc[a][g];
        }
        __syncthreads();
        if (kh == 0) {
            #pragma unroll
            for (int a = 0; a < 2; ++a)
                #pragma unroll
                for (int g = 0; g < 4; ++g) {
                    floatx4 t = *(const floatx4*)&ms[((((wv & 7) << 3) + (a << 2) + g) << 8) + (lane << 2)];
                    acc[a][g] += t;
                }
        }
    }

    if (kh == 0) {
        // ---- Stage D: GN partials ----
        #pragma unroll
        for (int a = 0; a < 2; ++a) {
            float s1 = 0.f, s2 = 0.f;
            #pragma unroll
            for (int g = 0; g < 4; ++g)
                #pragma unroll
                for (int r = 0; r < 4; ++r) {
                    float v = acc[a][g][r];
                    s1 += v; s2 += v * v;
                }
            #pragma unroll
            for (int off = 1; off <= 16; off <<= 1) {
                s1 += __shfl_xor(s1, off, 64);
                s2 += __shfl_xor(s2, off, 64);
            }
            if ((lane & 31) == 0) {
                int gg = (o0 >> 3) + (a << 1) + (lane >> 5);
                pstats[((long)bid << 6) + (gg << 1)]     = s1;
                pstats[((long)bid << 6) + (gg << 1) + 1] = s2;
            }
        }

        // ---- Stage E: raw stores ----
        if (nhwc) {
            u16* rb = raw + nbase + ((long)h << 14);   // (h*64+px)*256 + o
            #pragma unroll
            for (int a = 0; a < 2; ++a)
                #pragma unroll
                for (int g = 0; g < 4; ++g) {
                    int pxe = (g << 4) + l16;
                    int o = o0 + (a << 4) + (quad << 2);
                    u32 lo = cvtpk(acc[a][g][0], acc[a][g][1]);
                    u32 hi = cvtpk(acc[a][g][2], acc[a][g][3]);
                    *(uint2*)&rb[(pxe << 8) + o] = make_uint2(lo, hi);
                }
        } else {
            #pragma unroll
            for (int a = 0; a < 2; ++a)
                #pragma unroll
                for (int g = 0; g < 4; ++g)
                    #pragma unroll
                    for (int r = 0; r < 4; ++r) {
                        int o = o0 + (a << 4) + (quad << 2) + r;
                        raw[nbase + ((long)o << 12) + (h << 6) + (g << 4) + l16]
                            = f2bf(acc[a][g][r]);
                    }
        }
    }
}

// ---------------------------------------------------------------------------
// GN + relu, elementwise NHWC -> NHWC. 2048 blocks x 256 thr, 8 u16/thread.
// ---------------------------------------------------------------------------
__global__ __launch_bounds__(256) void k_gn_relu(
    const u16* __restrict__ raw, const float* __restrict__ pstats,
    const void* __restrict__ gamma, const void* __restrict__ beta,
    const u32* __restrict__ xw,
    u16* __restrict__ out1)
{
    __shared__ float sred[4][64];
    __shared__ float sl[64];
    const int f32 = sniff_f32(xw);
    const int tid = threadIdx.x;
    const int bid = blockIdx.x;          // 2048
    const int n = bid >> 9;

    {   // reduce partials: value v over 64 deform-blocks of this n
        const int v = tid & 63, part = tid >> 6;
        float a = 0.f;
        for (int j = part * 16; j < part * 16 + 16; ++j)
            a += pstats[(((long)n * 64 + j) << 6) + v];
        sred[part][v] = a;
        __syncthreads();
        if (tid < 64) sl[tid] = sred[0][tid] + sred[1][tid] + sred[2][tid] + sred[3][tid];
        __syncthreads();
    }

    const long i = (((long)bid) << 8) + tid;     // uint4 index
    const int c0 = (int)((i << 3) & 255);        // 8-aligned channel base
    const int g = c0 >> 3;                       // single group per thread
    float mean = sl[g * 2] * (1.f / 32768.f);
    float var  = sl[g * 2 + 1] * (1.f / 32768.f) - mean * mean;
    float rstd = rsqrtf(var + 1e-5f);

    float ga[8], be[8];
    if (f32) {
        float4 a0 = ((const float4*)gamma)[c0 >> 2];
        float4 a1 = ((const float4*)gamma)[(c0 >> 2) + 1];
        float4 b0 = ((const float4*)beta)[c0 >> 2];
        float4 b1 = ((const float4*)beta)[(c0 >> 2) + 1];
        ga[0]=a0.x; ga[1]=a0.y; ga[2]=a0.z; ga[3]=a0.w;
        ga[4]=a1.x; ga[5]=a1.y; ga[6]=a1.z; ga[7]=a1.w;
        be[0]=b0.x; be[1]=b0.y; be[2]=b0.z; be[3]=b0.w;
        be[4]=b1.x; be[5]=b1.y; be[6]=b1.z; be[7]=b1.w;
    } else {
        uint4 av = ((const uint4*)gamma)[c0 >> 3];
        uint4 bv = ((const uint4*)beta)[c0 >> 3];
        u32 aw[4] = {av.x, av.y, av.z, av.w};
        u32 bw[4] = {bv.x, bv.y, bv.z, bv.w};
        #pragma unroll
        for (int q = 0; q < 4; ++q) {
            ga[2*q] = bf2f((u16)(aw[q] & 0xFFFFu)); ga[2*q+1] = bf2f((u16)(aw[q] >> 16));
            be[2*q] = bf2f((u16)(bw[q] & 0xFFFFu)); be[2*q+1] = bf2f((u16)(bw[q] >> 16));
        }
    }

    uint4 p = ((const uint4*)raw)[i];
    u32 ww[4] = {p.x, p.y, p.z, p.w};
    u32 o[4];
    #pragma unroll
    for (int q = 0; q < 4; ++q) {
        float g0 = ga[2*q] * rstd,     g1 = ga[2*q+1] * rstd;
        float b0 = be[2*q] - mean*g0,  b1 = be[2*q+1] - mean*g1;
        float a = fmaxf(fmaf(bf2f((u16)(ww[q] & 0xFFFFu)), g0, b0), 0.f);
        float b = fmaxf(fmaf(bf2f((u16)(ww[q] >> 16)),     g1, b1), 0.f);
        o[q] = cvtpk(a, b);
    }
    ((uint4*)out1)[i] = make_uint4(o[0], o[1], o[2], o[3]);
}

// ---------------------------------------------------------------------------
// Final GN + residual + relu (pstats: 64 partials per n). raw is NCHW.
// ---------------------------------------------------------------------------
__global__ __launch_bounds__(256) void k_gn_final(
    const u16* __restrict__ raw, const float* __restrict__ pstats,
    const void* __restrict__ gamma, const void* __restrict__ beta,
    const void* __restrict__ x,
    void* __restrict__ outp)
{
    __shared__ float rr[256];
    const int f32 = sniff_f32((const u32*)x);
    const int tid = threadIdx.x;
    const long e0 = ((long)blockIdx.x) << 11;
    const int n = (int)(e0 >> 20);
    const int c0 = (int)((e0 >> 12) & 255);
    const int g = c0 >> 3;

    {
        int j = tid & 127, sv = tid >> 7;
        rr[tid] = (j < 64) ? pstats[(((long)n * 64 + j) << 6) + (g << 1) + sv] : 0.f;
        __syncthreads();
        #pragma unroll
        for (int s = 64; s >= 1; s >>= 1) {
            if ((tid & 127) < s) rr[tid] += rr[tid + s];
            __syncthreads();
        }
    }
    float mean = rr[0] * (1.f / 32768.f);
    float var  = rr[128] * (1.f / 32768.f) - mean * mean;
    float rstd = rsqrtf(var + 1e-5f);

    const long i = blockIdx.x * 256 + tid;
    const long e = i << 3;
    const int c = (int)((e >> 12) & 255);
    float ga = loadv(gamma, c, f32) * rstd;
    float be = loadv(beta, c, f32) - mean * ga;
    uint4 p = ((const uint4*)raw)[i];
    u32 ww[4] = {p.x, p.y, p.z, p.w};
    float v[8];
    #pragma unroll
    for (int q = 0; q < 4; ++q) {
        v[2 * q + 0] = fmaxf(fmaf(bf2f((u16)(ww[q] & 0xFFFFu)), ga, be) + loadv(x, e + 2 * q + 0, f32), 0.f);
        v[2 * q + 1] = fmaxf(fmaf(bf2f((u16)(ww[q] >> 16)),     ga, be) + loadv(x, e + 2 * q + 1, f32), 0.f);
    }
    if (f32) {
        float4* op = (float4*)((float*)outp + e);
        op[0] = make_float4(v[0], v[1], v[2], v[3]);
        op[1] = make_float4(v[4], v[5], v[6], v[7]);
    } else {
        uint4 o;
        o.x = cvtpk(v[0], v[1]);
        o.y = cvtpk(v[2], v[3]);
        o.z = cvtpk(v[4], v[5]);
        o.w = cvtpk(v[6], v[7]);
        ((uint4*)outp)[i] = o;
    }
}

extern "C" void kernel_launch(void* const* d_in, const int* in_sizes, int n_in,
                              void* d_out, int out_size, void* d_ws, size_t ws_size,
                              hipStream_t stream) {
    const void* x     = d_in[0];
    const void* w_tm1 = d_in[1];
    const void* b_tm1 = d_in[2];
    const void* w_tr1 = d_in[3];
    const void* b_tr1 = d_in[4];
    const void* w_dc1 = d_in[5];
    const void* g1    = d_in[6];
    const void* be1   = d_in[7];
    const void* w_tm2 = d_in[8];
    const void* b_tm2 = d_in[9];
    const void* w_tr2 = d_in[10];
    const void* b_tr2 = d_in[11];
    const void* w_dc2 = d_in[12];
    const void* g2    = d_in[13];
    const void* be2   = d_in[14];

    char* wsb = (char*)d_ws;
    u16*   xT     = (u16*)wsb;                       // 8,388,608 (alias out1)
    u16*   raw    = (u16*)(wsb + 8388608);           // 8,388,608
    u16*   wTg1   = (u16*)(wsb + 16777216);          // 1,179,648
    u16*   wTg2   = (u16*)(wsb + 17956864);          // 1,179,648
    u16*   wT61   = (u16*)(wsb + 19136512);          //    73,728
    u16*   wT62   = (u16*)(wsb + 19210240);          //    73,728
    float* pstats = (float*)(wsb + 19283968);        //   131,072
    u16*   out1   = xT;
    const u32* xw = (const u32*)x;

    k_prep_all<<<3104, 256, 0, stream>>>(x, w_dc1, w_dc2, w_tm1, w_tr1, w_tm2, w_tr2,
                                         xT, wTg1, wTg2, wT61, wT62);
    // ---- round 1 ----
    k_deform  <<<256, 1024, 0, stream>>>(xT, wTg1, wT61, b_tm1, b_tr1, xw, raw, pstats, 1);
    k_gn_relu <<<2048, 256, 0, stream>>>(raw, pstats, g1, be1, xw, out1);
    // ---- round 2 ----
    k_deform  <<<256, 1024, 0, stream>>>(out1, wTg2, wT62, b_tm2, b_tr2, xw, raw, pstats, 0);
    k_gn_final<<<2048, 256, 0, stream>>>(raw, pstats, g2, be2, x, d_out);
}